// Round 7
// baseline (640.471 us; speedup 1.0000x reference)
//
#include <hip/hip_runtime.h>

#define N_ITEMS 100000
#define EMB     128
#define N_EDGES 1600000
#define NLAYERS 3
#define NBINS   391    // ceil(100000 / 256) rows per bin = 256
#define CAP_BIN 4608   // avg 4096 edges/bin, +8 sigma slack

typedef unsigned short u16;
typedef unsigned int   u32;
typedef __attribute__((ext_vector_type(8))) short short8;   // 8 bf16 (4 VGPRs)
typedef __attribute__((ext_vector_type(4))) float f32x4;    // MFMA accumulator

__device__ __forceinline__ float bf2f(u16 u) {
    union { u32 i; float f; } v; v.i = (u32)u << 16; return v.f;
}
__device__ __forceinline__ u16 f2bf(float f) {
    union { float f; u32 i; } v; v.f = f;
    u32 b = v.i;
    return (u16)((b + 0x7FFFu + ((b >> 16) & 1u)) >> 16);  // RNE
}

// ---------------- fill pass 1: coarse bin scatter ----------------

__global__ __launch_bounds__(256) void fill_coarse_k(const int* __restrict__ rows,
                                                     const int* __restrict__ cols,
                                                     const float* __restrict__ vals,
                                                     int* __restrict__ bin_cnt,
                                                     int2* __restrict__ binbuf) {
    __shared__ int lcnt[NBINS];
    __shared__ int lbase[NBINS];
    int t = threadIdx.x;
    for (int d = t; d < NBINS; d += 256) lcnt[d] = 0;
    __syncthreads();
    int chunk = (N_EDGES + gridDim.x - 1) / gridDim.x;
    int e0 = blockIdx.x * chunk;
    int e1 = e0 + chunk; if (e1 > N_EDGES) e1 = N_EDGES;
    for (int e = e0 + t; e < e1; e += 256) {
        atomicAdd(&lcnt[rows[e] >> 8], 1);
    }
    __syncthreads();
    for (int d = t; d < NBINS; d += 256) {
        int c = lcnt[d];
        lbase[d] = c ? atomicAdd(&bin_cnt[d], c) : 0;
        lcnt[d] = 0;  // reuse as intra-block cursor
    }
    __syncthreads();
    for (int e = e0 + t; e < e1; e += 256) {
        int r = rows[e];
        int d = r >> 8;
        int p = lbase[d] + atomicAdd(&lcnt[d], 1);
        if (p < CAP_BIN) {
            int meta = ((r & 255) << 17) | cols[e];  // col < 2^17
            binbuf[(size_t)d * CAP_BIN + p] = make_int2(meta, __float_as_int(vals[e]));
        }
    }
}

// ---------------- fill pass 2: per-bin compact CSR in LDS ----------------
// csr meta stores col*256 (= byte offset of bf16 row) for 1-VALU gather addressing.

__global__ __launch_bounds__(256) void fill_fine_k(const int* __restrict__ bin_cnt,
                                                   const int2* __restrict__ binbuf,
                                                   int* __restrict__ cnt_g,
                                                   int* __restrict__ rstart_g,
                                                   int2* __restrict__ csr) {
    __shared__ int lcnt[256], loff[256], lcur[256], ltmp[256];
    int b = blockIdx.x, t = threadIdx.x;
    int ne = bin_cnt[b]; if (ne > CAP_BIN) ne = CAP_BIN;
    const int2* src = binbuf + (size_t)b * CAP_BIN;
    lcnt[t] = 0;
    __syncthreads();
    for (int i = t; i < ne; i += 256) {
        atomicAdd(&lcnt[src[i].x >> 17], 1);
    }
    __syncthreads();
    int v = lcnt[t];
    ltmp[t] = v;
    __syncthreads();
    for (int off = 1; off < 256; off <<= 1) {
        int x = (t >= off) ? ltmp[t - off] : 0;
        __syncthreads();
        ltmp[t] += x;
        __syncthreads();
    }
    loff[t] = ltmp[t] - v;  // exclusive
    lcur[t] = 0;
    int row = b * 256 + t;
    if (row < N_ITEMS) {
        cnt_g[row] = v;
        rstart_g[row] = b * CAP_BIN + loff[t];
    }
    __syncthreads();
    for (int i = t; i < ne; i += 256) {
        int2 ev = src[i];
        int rlow = ev.x >> 17;
        int col = ev.x & 0x1FFFF;
        int pos = loff[rlow] + atomicAdd(&lcur[rlow], 1);
        csr[(size_t)b * CAP_BIN + pos] = make_int2(col << 8, ev.y);
    }
}

// ---------------- W f32 -> bf16 ----------------

__global__ __launch_bounds__(256) void wconv_k(const float* __restrict__ W,
                                               u16* __restrict__ Wb) {
    int i = blockIdx.x * 256 + threadIdx.x;
    if (i < NLAYERS * EMB * EMB) Wb[i] = f2bf(W[i]);
}

// ---------------- emb -> bf16 ----------------

__global__ __launch_bounds__(256) void ebf_k(const float4* __restrict__ emb,
                                             ushort4* __restrict__ ebf) {
    int i = blockIdx.x * 256 + threadIdx.x;
    float4 v = emb[i];
    ushort4 u;
    u.x = f2bf(v.x); u.y = f2bf(v.y); u.z = f2bf(v.z); u.w = f2bf(v.w);
    ebf[i] = u;
}

// ---------------- fused layer: agg = spmm(h); hn = agg @ W^T; inv = 1/||hn|| ----
// Uses spmm/linear commutation: spmm(h @ W^T) == spmm(h) @ W^T.
// Block = 4 waves x 16 rows. Phase A: gather-aggregate (2 edges per wave-load,
// lanes 0-31 edge e / lanes 32-63 edge e+1, 8B per lane), agg -> swizzled LDS
// as bf16. Phase B: MFMA 16x16x32 (A from LDS, B = W from LDS; layout identical
// to round-5-verified gemm) + row-norm epilogue. No inter-wave barrier needed
// after W staging (agg LDS is wave-private).

__global__ __launch_bounds__(256) void layer_k(const u16* __restrict__ h,
                                               const int* __restrict__ rstart,
                                               const int* __restrict__ cnt,
                                               const int2* __restrict__ csr,
                                               const u16* __restrict__ Wb,
                                               u16* __restrict__ hn,
                                               float* __restrict__ inv) {
    __shared__ u16 Wl[128 * 136];
    __shared__ u16 Agg[4][16 * 128];  // per-wave 16 rows x 128 bf16, XOR-swizzled

    int t = threadIdx.x;
    {   // stage W (bf16) into padded LDS
        int j = t >> 1, c0 = (t & 1) * 64;
        const short8* src = (const short8*)(Wb + j * 128 + c0);
        #pragma unroll
        for (int q = 0; q < 8; q++) *(short8*)&Wl[j * 136 + c0 + q * 8] = src[q];
    }
    __syncthreads();

    int l = t & 63, w = t >> 6;
    int l5 = l & 31, half = l >> 5;
    int tileBase = blockIdx.x * 64 + w * 16;
    char* agg = (char*)Agg[w];

    // ---- phase A: gather + aggregate ----
    for (int rr = 0; rr < 16; rr++) {
        int row = tileBase + rr;
        if (row > N_ITEMS - 1) row = N_ITEMS - 1;
        int s = rstart[row], n = cnt[row];
        int2 my = make_int2(0, 0);              // lanes >= n stay (0,0):
        if (l < n) my = csr[(size_t)s + l];     // pad slots gather row 0 * 0.0
        float a0 = 0.f, a1 = 0.f, a2 = 0.f, a3 = 0.f;
        for (int j = 0; j < n; j += 4) {
            int i0 = j + half, i1 = j + 2 + half;
            int   c0 = __shfl(my.x, i0);
            float v0 = __int_as_float(__shfl(my.y, i0));
            int   c1 = __shfl(my.x, i1);
            float v1 = __int_as_float(__shfl(my.y, i1));
            ushort4 u0 = *(const ushort4*)((const char*)h + c0 + l5 * 8);
            ushort4 u1 = *(const ushort4*)((const char*)h + c1 + l5 * 8);
            a0 += v0 * bf2f(u0.x) + v1 * bf2f(u1.x);
            a1 += v0 * bf2f(u0.y) + v1 * bf2f(u1.y);
            a2 += v0 * bf2f(u0.z) + v1 * bf2f(u1.z);
            a3 += v0 * bf2f(u0.w) + v1 * bf2f(u1.w);
        }
        a0 += __shfl_xor(a0, 32);
        a1 += __shfl_xor(a1, 32);
        a2 += __shfl_xor(a2, 32);
        a3 += __shfl_xor(a3, 32);
        if (half == 0) {
            ushort4 o;
            o.x = f2bf(a0); o.y = f2bf(a1); o.z = f2bf(a2); o.w = f2bf(a3);
            int boff = (l5 * 8) ^ ((rr & 7) << 4);  // bank swizzle
            *(ushort4*)(agg + rr * 256 + boff) = o;
        }
    }

    // ---- phase B: MFMA + norm ----
    int g = l >> 4, r16 = l & 15;
    short8 a[4];
    #pragma unroll
    for (int kk = 0; kk < 4; kk++) {
        int boff = (kk * 64 + g * 16) ^ ((r16 & 7) << 4);
        a[kk] = *(const short8*)(agg + r16 * 256 + boff);
    }
    int rowD0 = tileBase + g * 4;
    float ssp[4] = {0.f, 0.f, 0.f, 0.f};
    #pragma unroll
    for (int jt = 0; jt < 8; jt++) {
        f32x4 acc = {0.f, 0.f, 0.f, 0.f};
        int rb = jt * 16 + r16;
        #pragma unroll
        for (int kk = 0; kk < 4; kk++) {
            short8 b = *(const short8*)&Wl[rb * 136 + kk * 32 + g * 8];
            acc = __builtin_amdgcn_mfma_f32_16x16x32_bf16(a[kk], b, acc, 0, 0, 0);
        }
        int col = jt * 16 + r16;
        #pragma unroll
        for (int i = 0; i < 4; i++) {
            ssp[i] += acc[i] * acc[i];
            int row = rowD0 + i;
            if (row < N_ITEMS) hn[(size_t)row * 128 + col] = f2bf(acc[i]);
        }
    }
    #pragma unroll
    for (int i = 0; i < 4; i++) {
        #pragma unroll
        for (int off = 1; off < 16; off <<= 1) ssp[i] += __shfl_xor(ssp[i], off);
    }
    if (r16 == 0) {
        #pragma unroll
        for (int i = 0; i < 4; i++) {
            int row = rowD0 + i;
            if (row < N_ITEMS) inv[row] = 1.0f / fmaxf(sqrtf(ssp[i]), 1e-12f);
        }
    }
}

// ---------------- merge: out = 0.25*(emb + sum_l hn_l * inv_l) ----------------

__global__ __launch_bounds__(256) void merge_k(const float4* __restrict__ emb4,
                                               const ushort4* __restrict__ h1,
                                               const ushort4* __restrict__ h2,
                                               const ushort4* __restrict__ h3,
                                               const float* __restrict__ inv1,
                                               const float* __restrict__ inv2,
                                               const float* __restrict__ inv3,
                                               float4* __restrict__ out4) {
    int i = blockIdx.x * 256 + threadIdx.x;  // N_ITEMS*32 elems
    int row = i >> 5;
    float i1 = inv1[row], i2 = inv2[row], i3 = inv3[row];
    float4 e = emb4[i];
    ushort4 a = h1[i], b = h2[i], c = h3[i];
    float4 o;
    o.x = 0.25f * (e.x + bf2f(a.x) * i1 + bf2f(b.x) * i2 + bf2f(c.x) * i3);
    o.y = 0.25f * (e.y + bf2f(a.y) * i1 + bf2f(b.y) * i2 + bf2f(c.y) * i3);
    o.z = 0.25f * (e.z + bf2f(a.z) * i1 + bf2f(b.z) * i2 + bf2f(c.z) * i3);
    o.w = 0.25f * (e.w + bf2f(a.w) * i1 + bf2f(b.w) * i2 + bf2f(c.w) * i3);
    out4[i] = o;
}

// ---------------- launch ----------------

extern "C" void kernel_launch(void* const* d_in, const int* in_sizes, int n_in,
                              void* d_out, int out_size, void* d_ws, size_t ws_size,
                              hipStream_t stream) {
    const float* emb  = (const float*)d_in[0];
    const float* vals = (const float*)d_in[1];
    const float* W    = (const float*)d_in[2];
    const int*   rows = (const int*)d_in[3];
    const int*   cols = (const int*)d_in[4];
    float* out = (float*)d_out;

    char* ws = (char*)d_ws;
    size_t off = 0;
    auto alloc = [&](size_t bytes) -> void* {
        void* p = ws + off;
        off = (off + bytes + 255) & ~(size_t)255;
        return p;
    };
    // arena: binbuf (CSR build) then reused as ebf (build finishes first)
    size_t ebf_sz = (size_t)N_ITEMS * 128 * 2;                  // 25.6 MB
    size_t bin_sz = (size_t)NBINS * CAP_BIN * 8;                // 14.4 MB
    char* arena = (char*)alloc(ebf_sz > bin_sz ? ebf_sz : bin_sz);
    int2* binbuf = (int2*)arena;
    u16*  ebf    = (u16*)arena;

    u16*  hn0     = (u16*)alloc((size_t)N_ITEMS * 128 * 2);
    u16*  hn1     = (u16*)alloc((size_t)N_ITEMS * 128 * 2);
    u16*  hn2     = (u16*)alloc((size_t)N_ITEMS * 128 * 2);
    int2* csr     = (int2*)alloc((size_t)NBINS * CAP_BIN * 8);
    int*  bin_cnt = (int*)alloc((size_t)NBINS * 4);
    int*  cnt_g   = (int*)alloc((size_t)N_ITEMS * 4);
    int*  rstart  = (int*)alloc((size_t)N_ITEMS * 4);
    float* inv0   = (float*)alloc((size_t)N_ITEMS * 4);
    float* inv1   = (float*)alloc((size_t)N_ITEMS * 4);
    float* inv2   = (float*)alloc((size_t)N_ITEMS * 4);
    u16*  Wbf     = (u16*)alloc((size_t)NLAYERS * EMB * EMB * 2);

    // CSR build (binned two-pass)
    hipMemsetAsync(bin_cnt, 0, (size_t)NBINS * 4, stream);
    fill_coarse_k<<<512, 256, 0, stream>>>(rows, cols, vals, bin_cnt, binbuf);
    fill_fine_k<<<NBINS, 256, 0, stream>>>(bin_cnt, binbuf, cnt_g, rstart, csr);

    // W -> bf16; emb -> bf16 (ebf aliases binbuf: build is complete)
    wconv_k<<<(NLAYERS * EMB * EMB + 255) / 256, 256, 0, stream>>>(W, Wbf);
    ebf_k<<<(N_ITEMS * 128 / 4) / 256, 256, 0, stream>>>((const float4*)emb,
                                                         (ushort4*)ebf);

    // 3 fused layers
    u16* hn[3] = {hn0, hn1, hn2};
    float* inv[3] = {inv0, inv1, inv2};
    const u16* cur = ebf;
    for (int L = 0; L < NLAYERS; L++) {
        layer_k<<<(N_ITEMS + 63) / 64, 256, 0, stream>>>(
            cur, rstart, cnt_g, csr, Wbf + (size_t)L * EMB * EMB, hn[L], inv[L]);
        cur = hn[L];
    }

    // final merge
    merge_k<<<(N_ITEMS * 128 / 4) / 256, 256, 0, stream>>>(
        (const float4*)emb, (const ushort4*)hn0, (const ushort4*)hn1,
        (const ushort4*)hn2, inv0, inv1, inv2, (float4*)out);
}

// Round 8
// 432.291 us; speedup vs baseline: 1.4816x; 1.4816x over previous
//
#include <hip/hip_runtime.h>

#define N_ITEMS 100000
#define EMB     128
#define N_EDGES 1600000
#define NLAYERS 3
#define NBINS   391    // ceil(100000 / 256) rows per bin = 256
#define CAP_BIN 4608   // avg 4096 edges/bin, +8 sigma slack

typedef unsigned short u16;
typedef unsigned int   u32;
typedef __attribute__((ext_vector_type(8))) short short8;   // 8 bf16 (4 VGPRs)
typedef __attribute__((ext_vector_type(4))) float f32x4;    // MFMA accumulator

__device__ __forceinline__ float bf2f(u16 u) {
    union { u32 i; float f; } v; v.i = (u32)u << 16; return v.f;
}
__device__ __forceinline__ u16 f2bf(float f) {
    union { float f; u32 i; } v; v.f = f;
    u32 b = v.i;
    return (u16)((b + 0x7FFFu + ((b >> 16) & 1u)) >> 16);  // RNE
}

// ---------------- fill pass 1: coarse bin scatter ----------------

__global__ __launch_bounds__(256) void fill_coarse_k(const int* __restrict__ rows,
                                                     const int* __restrict__ cols,
                                                     const float* __restrict__ vals,
                                                     int* __restrict__ bin_cnt,
                                                     int2* __restrict__ binbuf) {
    __shared__ int lcnt[NBINS];
    __shared__ int lbase[NBINS];
    int t = threadIdx.x;
    for (int d = t; d < NBINS; d += 256) lcnt[d] = 0;
    __syncthreads();
    int chunk = (N_EDGES + gridDim.x - 1) / gridDim.x;
    int e0 = blockIdx.x * chunk;
    int e1 = e0 + chunk; if (e1 > N_EDGES) e1 = N_EDGES;
    for (int e = e0 + t; e < e1; e += 256) {
        atomicAdd(&lcnt[rows[e] >> 8], 1);
    }
    __syncthreads();
    for (int d = t; d < NBINS; d += 256) {
        int c = lcnt[d];
        lbase[d] = c ? atomicAdd(&bin_cnt[d], c) : 0;
        lcnt[d] = 0;  // reuse as intra-block cursor
    }
    __syncthreads();
    for (int e = e0 + t; e < e1; e += 256) {
        int r = rows[e];
        int d = r >> 8;
        int p = lbase[d] + atomicAdd(&lcnt[d], 1);
        if (p < CAP_BIN) {
            int meta = ((r & 255) << 17) | cols[e];  // col < 2^17
            binbuf[(size_t)d * CAP_BIN + p] = make_int2(meta, __float_as_int(vals[e]));
        }
    }
}

// ---------------- fill pass 2: per-bin compact CSR in LDS ----------------

__global__ __launch_bounds__(256) void fill_fine_k(const int* __restrict__ bin_cnt,
                                                   const int2* __restrict__ binbuf,
                                                   int* __restrict__ cnt_g,
                                                   int* __restrict__ rstart_g,
                                                   int2* __restrict__ csr) {
    __shared__ int lcnt[256], loff[256], lcur[256], ltmp[256];
    int b = blockIdx.x, t = threadIdx.x;
    int ne = bin_cnt[b]; if (ne > CAP_BIN) ne = CAP_BIN;
    const int2* src = binbuf + (size_t)b * CAP_BIN;
    lcnt[t] = 0;
    __syncthreads();
    for (int i = t; i < ne; i += 256) {
        atomicAdd(&lcnt[src[i].x >> 17], 1);
    }
    __syncthreads();
    int v = lcnt[t];
    ltmp[t] = v;
    __syncthreads();
    for (int off = 1; off < 256; off <<= 1) {
        int x = (t >= off) ? ltmp[t - off] : 0;
        __syncthreads();
        ltmp[t] += x;
        __syncthreads();
    }
    loff[t] = ltmp[t] - v;  // exclusive
    lcur[t] = 0;
    int row = b * 256 + t;
    if (row < N_ITEMS) {
        cnt_g[row] = v;
        rstart_g[row] = b * CAP_BIN + loff[t];
    }
    __syncthreads();
    for (int i = t; i < ne; i += 256) {
        int2 ev = src[i];
        int rlow = ev.x >> 17;
        int col = ev.x & 0x1FFFF;
        int pos = loff[rlow] + atomicAdd(&lcur[rlow], 1);
        csr[(size_t)b * CAP_BIN + pos] = make_int2(col, ev.y);
    }
}

// ---------------- W f32 -> bf16 ----------------

__global__ __launch_bounds__(256) void wconv_k(const float* __restrict__ W,
                                               u16* __restrict__ Wb) {
    int i = blockIdx.x * 256 + threadIdx.x;
    if (i < NLAYERS * EMB * EMB) Wb[i] = f2bf(W[i]);
}

// ---------------- MFMA GEMM: out[n][j] = sum_k in[n][k] * W[j][k] ----------------
// bf16 (or f32 layer-0) in, bf16 out, f32 accum. 128 rows per block (grid 782),
// W staged once per block, 2 subtiles of 64 rows per wave pass. MFMA layout
// verified in round 5.

template <bool F32IN>
__global__ __launch_bounds__(256) void gemm_k(const void* __restrict__ inp,
                                              const u16* __restrict__ Wb,
                                              u16* __restrict__ out) {
    __shared__ u16 Wl[128 * 136];
    int t = threadIdx.x;
    {
        int j = t >> 1, c0 = (t & 1) * 64;
        const short8* src = (const short8*)(Wb + j * 128 + c0);
        #pragma unroll
        for (int q = 0; q < 8; q++) *(short8*)&Wl[j * 136 + c0 + q * 8] = src[q];
    }
    __syncthreads();

    int l = t & 63, w = t >> 6;
    int g = l >> 4, r16 = l & 15;

    for (int tt = 0; tt < 2; tt++) {
        int rowA = blockIdx.x * 128 + tt * 64 + w * 16 + r16;
        if (rowA > N_ITEMS - 1) rowA = N_ITEMS - 1;

        short8 a[4];
        if (F32IN) {
            const float* inf = (const float*)inp + (size_t)rowA * 128;
            #pragma unroll
            for (int kk = 0; kk < 4; kk++) {
                float4 p0 = *(const float4*)(inf + kk * 32 + g * 8);
                float4 p1 = *(const float4*)(inf + kk * 32 + g * 8 + 4);
                short8 s;
                s[0] = (short)f2bf(p0.x); s[1] = (short)f2bf(p0.y);
                s[2] = (short)f2bf(p0.z); s[3] = (short)f2bf(p0.w);
                s[4] = (short)f2bf(p1.x); s[5] = (short)f2bf(p1.y);
                s[6] = (short)f2bf(p1.z); s[7] = (short)f2bf(p1.w);
                a[kk] = s;
            }
        } else {
            const u16* inb = (const u16*)inp + (size_t)rowA * 128;
            #pragma unroll
            for (int kk = 0; kk < 4; kk++) {
                a[kk] = *(const short8*)(inb + kk * 32 + g * 8);
            }
        }

        int rowD0 = blockIdx.x * 128 + tt * 64 + w * 16 + g * 4;
        #pragma unroll
        for (int jt = 0; jt < 8; jt++) {
            f32x4 acc = {0.f, 0.f, 0.f, 0.f};
            int rb = jt * 16 + r16;
            #pragma unroll
            for (int kk = 0; kk < 4; kk++) {
                short8 bfr = *(const short8*)&Wl[rb * 136 + kk * 32 + g * 8];
                acc = __builtin_amdgcn_mfma_f32_16x16x32_bf16(a[kk], bfr, acc, 0, 0, 0);
            }
            int col = jt * 16 + r16;
            #pragma unroll
            for (int i = 0; i < 4; i++) {
                int row = rowD0 + i;
                if (row < N_ITEMS) out[(size_t)row * 128 + col] = f2bf(acc[i]);
            }
        }
    }
}

// ---------------- SpMM + norm scalar (no acc RMW) ----------------
// One wave per row; lane owns dims {2*lane, 2*lane+1}. Edge (col,val) read at
// a WAVE-UNIFORM address (SGPR-eligible, broadcast L1 hit) -- replaces the
// coalesced-chunk + 2x ds_bpermute broadcast of round 6. 4-deep gather ILP.
// No LDS, ~20 VGPR => occupancy stays high (the round-7 fusion lesson).

__global__ __launch_bounds__(256) void spmm_k(const u16* __restrict__ h,
                                              const int* __restrict__ rstart,
                                              const int* __restrict__ cnt,
                                              const int2* __restrict__ csr,
                                              u16* __restrict__ hn,
                                              float* __restrict__ inv) {
    int wid = (blockIdx.x * 256 + threadIdx.x) >> 6;
    int lane = threadIdx.x & 63;
    if (wid >= N_ITEMS) return;
    int s = __builtin_amdgcn_readfirstlane(rstart[wid]);
    int n = __builtin_amdgcn_readfirstlane(cnt[wid]);

    const char* hB = (const char*)h;
    size_t loff = (size_t)lane * 4;
    float a0 = 0.f, a1 = 0.f;
    int j = 0;
    for (; j + 4 <= n; j += 4) {
        int2 e0 = csr[s + j + 0];
        int2 e1 = csr[s + j + 1];
        int2 e2 = csr[s + j + 2];
        int2 e3 = csr[s + j + 3];
        ushort2 u0 = *(const ushort2*)(hB + (((size_t)(u32)e0.x) << 8) + loff);
        ushort2 u1 = *(const ushort2*)(hB + (((size_t)(u32)e1.x) << 8) + loff);
        ushort2 u2 = *(const ushort2*)(hB + (((size_t)(u32)e2.x) << 8) + loff);
        ushort2 u3 = *(const ushort2*)(hB + (((size_t)(u32)e3.x) << 8) + loff);
        float v0 = __int_as_float(e0.y), v1 = __int_as_float(e1.y);
        float v2 = __int_as_float(e2.y), v3 = __int_as_float(e3.y);
        a0 += v0 * bf2f(u0.x); a1 += v0 * bf2f(u0.y);
        a0 += v1 * bf2f(u1.x); a1 += v1 * bf2f(u1.y);
        a0 += v2 * bf2f(u2.x); a1 += v2 * bf2f(u2.y);
        a0 += v3 * bf2f(u3.x); a1 += v3 * bf2f(u3.y);
    }
    for (; j < n; j++) {
        int2 e0 = csr[s + j];
        ushort2 u0 = *(const ushort2*)(hB + (((size_t)(u32)e0.x) << 8) + loff);
        float v0 = __int_as_float(e0.y);
        a0 += v0 * bf2f(u0.x); a1 += v0 * bf2f(u0.y);
    }

    float ss = a0 * a0 + a1 * a1;
    #pragma unroll
    for (int off = 32; off > 0; off >>= 1) ss += __shfl_xor(ss, off);
    ushort2 o;
    o.x = f2bf(a0);
    o.y = f2bf(a1);
    ((ushort2*)hn)[(size_t)wid * 64 + lane] = o;
    if (lane == 0) inv[wid] = 1.0f / fmaxf(sqrtf(ss), 1e-12f);
}

// ---------------- merge: out = 0.25*(emb + sum_l hn_l * inv_l) ----------------

__global__ __launch_bounds__(256) void merge_k(const float4* __restrict__ emb4,
                                               const ushort4* __restrict__ h1,
                                               const ushort4* __restrict__ h2,
                                               const ushort4* __restrict__ h3,
                                               const float* __restrict__ inv1,
                                               const float* __restrict__ inv2,
                                               const float* __restrict__ inv3,
                                               float4* __restrict__ out4) {
    int i = blockIdx.x * 256 + threadIdx.x;  // N_ITEMS*32 elems
    int row = i >> 5;
    float i1 = inv1[row], i2 = inv2[row], i3 = inv3[row];
    float4 e = emb4[i];
    ushort4 a = h1[i], b = h2[i], c = h3[i];
    float4 o;
    o.x = 0.25f * (e.x + bf2f(a.x) * i1 + bf2f(b.x) * i2 + bf2f(c.x) * i3);
    o.y = 0.25f * (e.y + bf2f(a.y) * i1 + bf2f(b.y) * i2 + bf2f(c.y) * i3);
    o.z = 0.25f * (e.z + bf2f(a.z) * i1 + bf2f(b.z) * i2 + bf2f(c.z) * i3);
    o.w = 0.25f * (e.w + bf2f(a.w) * i1 + bf2f(b.w) * i2 + bf2f(c.w) * i3);
    out4[i] = o;
}

// ---------------- launch ----------------

extern "C" void kernel_launch(void* const* d_in, const int* in_sizes, int n_in,
                              void* d_out, int out_size, void* d_ws, size_t ws_size,
                              hipStream_t stream) {
    const float* emb  = (const float*)d_in[0];
    const float* vals = (const float*)d_in[1];
    const float* W    = (const float*)d_in[2];
    const int*   rows = (const int*)d_in[3];
    const int*   cols = (const int*)d_in[4];
    float* out = (float*)d_out;

    char* ws = (char*)d_ws;
    size_t off = 0;
    auto alloc = [&](size_t bytes) -> void* {
        void* p = ws + off;
        off = (off + bytes + 255) & ~(size_t)255;
        return p;
    };
    // arena: binbuf (CSR build) then reused as gemm output gbuf (build done first)
    size_t g_sz   = (size_t)N_ITEMS * 128 * 2;                  // 25.6 MB
    size_t bin_sz = (size_t)NBINS * CAP_BIN * 8;                // 14.4 MB
    char* arena = (char*)alloc(g_sz > bin_sz ? g_sz : bin_sz);
    int2* binbuf = (int2*)arena;
    u16*  gbuf   = (u16*)arena;

    u16*  hn0     = (u16*)alloc((size_t)N_ITEMS * 128 * 2);
    u16*  hn1     = (u16*)alloc((size_t)N_ITEMS * 128 * 2);
    u16*  hn2     = (u16*)alloc((size_t)N_ITEMS * 128 * 2);
    int2* csr     = (int2*)alloc((size_t)NBINS * CAP_BIN * 8);
    int*  bin_cnt = (int*)alloc((size_t)NBINS * 4);
    int*  cnt_g   = (int*)alloc((size_t)N_ITEMS * 4);
    int*  rstart  = (int*)alloc((size_t)N_ITEMS * 4);
    float* inv0   = (float*)alloc((size_t)N_ITEMS * 4);
    float* inv1   = (float*)alloc((size_t)N_ITEMS * 4);
    float* inv2   = (float*)alloc((size_t)N_ITEMS * 4);
    u16*  Wbf     = (u16*)alloc((size_t)NLAYERS * EMB * EMB * 2);

    // CSR build (binned two-pass)
    hipMemsetAsync(bin_cnt, 0, (size_t)NBINS * 4, stream);
    fill_coarse_k<<<512, 256, 0, stream>>>(rows, cols, vals, bin_cnt, binbuf);
    fill_fine_k<<<NBINS, 256, 0, stream>>>(bin_cnt, binbuf, cnt_g, rstart, csr);

    // W -> bf16
    wconv_k<<<(NLAYERS * EMB * EMB + 255) / 256, 256, 0, stream>>>(W, Wbf);

    // 3 layers: gemm (layer 0 reads f32 emb directly) then spmm
    u16* hn[3] = {hn0, hn1, hn2};
    float* inv[3] = {inv0, inv1, inv2};
    const void* cur = emb;
    for (int L = 0; L < NLAYERS; L++) {
        if (L == 0)
            gemm_k<true><<<(N_ITEMS + 127) / 128, 256, 0, stream>>>(cur, Wbf, gbuf);
        else
            gemm_k<false><<<(N_ITEMS + 127) / 128, 256, 0, stream>>>(cur, Wbf + (size_t)L * EMB * EMB, gbuf);
        spmm_k<<<N_ITEMS / 4, 256, 0, stream>>>(gbuf, rstart, cnt_g, csr, hn[L], inv[L]);
        cur = hn[L];
    }

    // final merge
    merge_k<<<(N_ITEMS * 128 / 4) / 256, 256, 0, stream>>>(
        (const float4*)emb, (const ushort4*)hn0, (const ushort4*)hn1,
        (const ushort4*)hn2, inv0, inv1, inv2, (float4*)out);
}

// Round 9
// 408.652 us; speedup vs baseline: 1.5673x; 1.0578x over previous
//
#include <hip/hip_runtime.h>

#define N_ITEMS 100000
#define EMB     128
#define N_EDGES 1600000
#define NLAYERS 3
#define NBINS   391    // ceil(100000 / 256) rows per bin = 256
#define CAP_BIN 4608   // avg 4096 edges/bin, +8 sigma slack

typedef unsigned short u16;
typedef unsigned int   u32;
typedef __attribute__((ext_vector_type(8))) short short8;   // 8 bf16 (4 VGPRs)
typedef __attribute__((ext_vector_type(4))) float f32x4;    // MFMA accumulator

__device__ __forceinline__ float bf2f(u16 u) {
    union { u32 i; float f; } v; v.i = (u32)u << 16; return v.f;
}
__device__ __forceinline__ u16 f2bf(float f) {
    union { float f; u32 i; } v; v.f = f;
    u32 b = v.i;
    return (u16)((b + 0x7FFFu + ((b >> 16) & 1u)) >> 16);  // RNE
}

// ---------------- fill pass 1: coarse bin scatter (int4-vectorized) ----------------
// Grid-stride by gid over 4-edge packets; both passes iterate the identical
// per-block edge set, so the per-(block,bin) range reservation stays valid.

__global__ __launch_bounds__(256) void fill_coarse_k(const int* __restrict__ rows,
                                                     const int* __restrict__ cols,
                                                     const float* __restrict__ vals,
                                                     int* __restrict__ bin_cnt,
                                                     int2* __restrict__ binbuf) {
    __shared__ int lcnt[NBINS];
    __shared__ int lbase[NBINS];
    int t = threadIdx.x;
    for (int d = t; d < NBINS; d += 256) lcnt[d] = 0;
    __syncthreads();
    int gid0 = blockIdx.x * 256 + t;
    const int GSTRIDE = 512 * 256;
    // pass 1: histogram
    for (int g = gid0; g * 4 < N_EDGES; g += GSTRIDE) {
        int4 r4 = *(const int4*)(rows + g * 4);
        atomicAdd(&lcnt[r4.x >> 8], 1);
        atomicAdd(&lcnt[r4.y >> 8], 1);
        atomicAdd(&lcnt[r4.z >> 8], 1);
        atomicAdd(&lcnt[r4.w >> 8], 1);
    }
    __syncthreads();
    for (int d = t; d < NBINS; d += 256) {
        int c = lcnt[d];
        lbase[d] = c ? atomicAdd(&bin_cnt[d], c) : 0;
        lcnt[d] = 0;  // reuse as intra-block cursor
    }
    __syncthreads();
    // pass 2: scatter
    for (int g = gid0; g * 4 < N_EDGES; g += GSTRIDE) {
        int e = g * 4;
        int4   r4 = *(const int4*)(rows + e);
        int4   c4 = *(const int4*)(cols + e);
        float4 v4 = *(const float4*)(vals + e);
        int rr[4] = {r4.x, r4.y, r4.z, r4.w};
        int cc[4] = {c4.x, c4.y, c4.z, c4.w};
        float vv[4] = {v4.x, v4.y, v4.z, v4.w};
        #pragma unroll
        for (int q = 0; q < 4; q++) {
            int r = rr[q];
            int d = r >> 8;
            int p = lbase[d] + atomicAdd(&lcnt[d], 1);
            if (p < CAP_BIN) {
                int meta = ((r & 255) << 17) | cc[q];  // col < 2^17
                binbuf[(size_t)d * CAP_BIN + p] = make_int2(meta, __float_as_int(vv[q]));
            }
        }
    }
}

// ---------------- fill pass 2: per-bin compact CSR in LDS ----------------
// csr meta stores col*256 = byte offset into the bf16 h matrix (saves one
// VALU shift per edge per gather in spmm_k).

__global__ __launch_bounds__(256) void fill_fine_k(const int* __restrict__ bin_cnt,
                                                   const int2* __restrict__ binbuf,
                                                   int* __restrict__ cnt_g,
                                                   int* __restrict__ rstart_g,
                                                   int2* __restrict__ csr) {
    __shared__ int lcnt[256], loff[256], lcur[256], ltmp[256];
    int b = blockIdx.x, t = threadIdx.x;
    int ne = bin_cnt[b]; if (ne > CAP_BIN) ne = CAP_BIN;
    const int2* src = binbuf + (size_t)b * CAP_BIN;
    const int4* src4 = (const int4*)src;
    int ne2 = ne >> 1;
    lcnt[t] = 0;
    __syncthreads();
    for (int i = t; i < ne2; i += 256) {
        int4 p = src4[i];
        atomicAdd(&lcnt[p.x >> 17], 1);
        atomicAdd(&lcnt[p.z >> 17], 1);
    }
    if (t == 0 && (ne & 1)) atomicAdd(&lcnt[src[ne - 1].x >> 17], 1);
    __syncthreads();
    int v = lcnt[t];
    ltmp[t] = v;
    __syncthreads();
    for (int off = 1; off < 256; off <<= 1) {
        int x = (t >= off) ? ltmp[t - off] : 0;
        __syncthreads();
        ltmp[t] += x;
        __syncthreads();
    }
    loff[t] = ltmp[t] - v;  // exclusive
    lcur[t] = 0;
    int row = b * 256 + t;
    if (row < N_ITEMS) {
        cnt_g[row] = v;
        rstart_g[row] = b * CAP_BIN + loff[t];
    }
    __syncthreads();
    for (int i = t; i < ne2; i += 256) {
        int4 p = src4[i];
        int rl0 = p.x >> 17, cl0 = p.x & 0x1FFFF;
        int rl1 = p.z >> 17, cl1 = p.z & 0x1FFFF;
        int pos0 = loff[rl0] + atomicAdd(&lcur[rl0], 1);
        csr[(size_t)b * CAP_BIN + pos0] = make_int2(cl0 << 8, p.y);
        int pos1 = loff[rl1] + atomicAdd(&lcur[rl1], 1);
        csr[(size_t)b * CAP_BIN + pos1] = make_int2(cl1 << 8, p.w);
    }
    if (t == 0 && (ne & 1)) {
        int2 ev = src[ne - 1];
        int rl = ev.x >> 17, cl = ev.x & 0x1FFFF;
        int pos = loff[rl] + atomicAdd(&lcur[rl], 1);
        csr[(size_t)b * CAP_BIN + pos] = make_int2(cl << 8, ev.y);
    }
}

// ---------------- W f32 -> bf16 ----------------

__global__ __launch_bounds__(256) void wconv_k(const float* __restrict__ W,
                                               u16* __restrict__ Wb) {
    int i = blockIdx.x * 256 + threadIdx.x;
    if (i < NLAYERS * EMB * EMB) Wb[i] = f2bf(W[i]);
}

// ---------------- MFMA GEMM: out[n][j] = sum_k in[n][k] * W[j][k] ----------------
// bf16 (or f32 layer-0) in, bf16 out, f32 accum. 128 rows per block (grid 782),
// W staged once per block, 2 subtiles of 64 rows per wave pass. MFMA layout
// verified in round 5.

template <bool F32IN>
__global__ __launch_bounds__(256) void gemm_k(const void* __restrict__ inp,
                                              const u16* __restrict__ Wb,
                                              u16* __restrict__ out) {
    __shared__ u16 Wl[128 * 136];
    int t = threadIdx.x;
    {
        int j = t >> 1, c0 = (t & 1) * 64;
        const short8* src = (const short8*)(Wb + j * 128 + c0);
        #pragma unroll
        for (int q = 0; q < 8; q++) *(short8*)&Wl[j * 136 + c0 + q * 8] = src[q];
    }
    __syncthreads();

    int l = t & 63, w = t >> 6;
    int g = l >> 4, r16 = l & 15;

    for (int tt = 0; tt < 2; tt++) {
        int rowA = blockIdx.x * 128 + tt * 64 + w * 16 + r16;
        if (rowA > N_ITEMS - 1) rowA = N_ITEMS - 1;

        short8 a[4];
        if (F32IN) {
            const float* inf = (const float*)inp + (size_t)rowA * 128;
            #pragma unroll
            for (int kk = 0; kk < 4; kk++) {
                float4 p0 = *(const float4*)(inf + kk * 32 + g * 8);
                float4 p1 = *(const float4*)(inf + kk * 32 + g * 8 + 4);
                short8 s;
                s[0] = (short)f2bf(p0.x); s[1] = (short)f2bf(p0.y);
                s[2] = (short)f2bf(p0.z); s[3] = (short)f2bf(p0.w);
                s[4] = (short)f2bf(p1.x); s[5] = (short)f2bf(p1.y);
                s[6] = (short)f2bf(p1.z); s[7] = (short)f2bf(p1.w);
                a[kk] = s;
            }
        } else {
            const u16* inb = (const u16*)inp + (size_t)rowA * 128;
            #pragma unroll
            for (int kk = 0; kk < 4; kk++) {
                a[kk] = *(const short8*)(inb + kk * 32 + g * 8);
            }
        }

        int rowD0 = blockIdx.x * 128 + tt * 64 + w * 16 + g * 4;
        #pragma unroll
        for (int jt = 0; jt < 8; jt++) {
            f32x4 acc = {0.f, 0.f, 0.f, 0.f};
            int rb = jt * 16 + r16;
            #pragma unroll
            for (int kk = 0; kk < 4; kk++) {
                short8 bfr = *(const short8*)&Wl[rb * 136 + kk * 32 + g * 8];
                acc = __builtin_amdgcn_mfma_f32_16x16x32_bf16(a[kk], bfr, acc, 0, 0, 0);
            }
            int col = jt * 16 + r16;
            #pragma unroll
            for (int i = 0; i < 4; i++) {
                int row = rowD0 + i;
                if (row < N_ITEMS) out[(size_t)row * 128 + col] = f2bf(acc[i]);
            }
        }
    }
}

// ---------------- SpMM + norm scalar ----------------
// One wave per row; lane owns dims {2*lane, 2*lane+1}. Edge descriptors read
// at wave-uniform addresses (s_load-eligible); csr.x is a precomputed byte
// offset; per-lane base pointer. 8-deep gather ILP, no LDS, ~30 VGPR.

__global__ __launch_bounds__(256) void spmm_k(const u16* __restrict__ h,
                                              const int* __restrict__ rstart,
                                              const int* __restrict__ cnt,
                                              const int2* __restrict__ csr,
                                              u16* __restrict__ hn,
                                              float* __restrict__ inv) {
    int wid = (blockIdx.x * 256 + threadIdx.x) >> 6;
    int lane = threadIdx.x & 63;
    if (wid >= N_ITEMS) return;
    int s = __builtin_amdgcn_readfirstlane(rstart[wid]);
    int n = __builtin_amdgcn_readfirstlane(cnt[wid]);

    const char* hL = (const char*)h + (size_t)lane * 4;  // per-lane base
    float a0 = 0.f, a1 = 0.f;
    int j = 0;
    for (; j + 8 <= n; j += 8) {
        int2 e0 = csr[s + j + 0];
        int2 e1 = csr[s + j + 1];
        int2 e2 = csr[s + j + 2];
        int2 e3 = csr[s + j + 3];
        int2 e4 = csr[s + j + 4];
        int2 e5 = csr[s + j + 5];
        int2 e6 = csr[s + j + 6];
        int2 e7 = csr[s + j + 7];
        ushort2 u0 = *(const ushort2*)(hL + (u32)e0.x);
        ushort2 u1 = *(const ushort2*)(hL + (u32)e1.x);
        ushort2 u2 = *(const ushort2*)(hL + (u32)e2.x);
        ushort2 u3 = *(const ushort2*)(hL + (u32)e3.x);
        ushort2 u4 = *(const ushort2*)(hL + (u32)e4.x);
        ushort2 u5 = *(const ushort2*)(hL + (u32)e5.x);
        ushort2 u6 = *(const ushort2*)(hL + (u32)e6.x);
        ushort2 u7 = *(const ushort2*)(hL + (u32)e7.x);
        float v0 = __int_as_float(e0.y), v1 = __int_as_float(e1.y);
        float v2 = __int_as_float(e2.y), v3 = __int_as_float(e3.y);
        float v4 = __int_as_float(e4.y), v5 = __int_as_float(e5.y);
        float v6 = __int_as_float(e6.y), v7 = __int_as_float(e7.y);
        a0 += v0 * bf2f(u0.x); a1 += v0 * bf2f(u0.y);
        a0 += v1 * bf2f(u1.x); a1 += v1 * bf2f(u1.y);
        a0 += v2 * bf2f(u2.x); a1 += v2 * bf2f(u2.y);
        a0 += v3 * bf2f(u3.x); a1 += v3 * bf2f(u3.y);
        a0 += v4 * bf2f(u4.x); a1 += v4 * bf2f(u4.y);
        a0 += v5 * bf2f(u5.x); a1 += v5 * bf2f(u5.y);
        a0 += v6 * bf2f(u6.x); a1 += v6 * bf2f(u6.y);
        a0 += v7 * bf2f(u7.x); a1 += v7 * bf2f(u7.y);
    }
    for (; j + 2 <= n; j += 2) {
        int2 e0 = csr[s + j + 0];
        int2 e1 = csr[s + j + 1];
        ushort2 u0 = *(const ushort2*)(hL + (u32)e0.x);
        ushort2 u1 = *(const ushort2*)(hL + (u32)e1.x);
        float v0 = __int_as_float(e0.y), v1 = __int_as_float(e1.y);
        a0 += v0 * bf2f(u0.x); a1 += v0 * bf2f(u0.y);
        a0 += v1 * bf2f(u1.x); a1 += v1 * bf2f(u1.y);
    }
    if (j < n) {
        int2 e0 = csr[s + j];
        ushort2 u0 = *(const ushort2*)(hL + (u32)e0.x);
        float v0 = __int_as_float(e0.y);
        a0 += v0 * bf2f(u0.x); a1 += v0 * bf2f(u0.y);
    }

    float ss = a0 * a0 + a1 * a1;
    #pragma unroll
    for (int off = 32; off > 0; off >>= 1) ss += __shfl_xor(ss, off);
    ushort2 o;
    o.x = f2bf(a0);
    o.y = f2bf(a1);
    ((ushort2*)hn)[(size_t)wid * 64 + lane] = o;
    if (lane == 0) inv[wid] = 1.0f / fmaxf(sqrtf(ss), 1e-12f);
}

// ---------------- merge: out = 0.25*(emb + sum_l hn_l * inv_l) ----------------

__global__ __launch_bounds__(256) void merge_k(const float4* __restrict__ emb4,
                                               const ushort4* __restrict__ h1,
                                               const ushort4* __restrict__ h2,
                                               const ushort4* __restrict__ h3,
                                               const float* __restrict__ inv1,
                                               const float* __restrict__ inv2,
                                               const float* __restrict__ inv3,
                                               float4* __restrict__ out4) {
    int i = blockIdx.x * 256 + threadIdx.x;  // N_ITEMS*32 elems
    int row = i >> 5;
    float i1 = inv1[row], i2 = inv2[row], i3 = inv3[row];
    float4 e = emb4[i];
    ushort4 a = h1[i], b = h2[i], c = h3[i];
    float4 o;
    o.x = 0.25f * (e.x + bf2f(a.x) * i1 + bf2f(b.x) * i2 + bf2f(c.x) * i3);
    o.y = 0.25f * (e.y + bf2f(a.y) * i1 + bf2f(b.y) * i2 + bf2f(c.y) * i3);
    o.z = 0.25f * (e.z + bf2f(a.z) * i1 + bf2f(b.z) * i2 + bf2f(c.z) * i3);
    o.w = 0.25f * (e.w + bf2f(a.w) * i1 + bf2f(b.w) * i2 + bf2f(c.w) * i3);
    out4[i] = o;
}

// ---------------- launch ----------------

extern "C" void kernel_launch(void* const* d_in, const int* in_sizes, int n_in,
                              void* d_out, int out_size, void* d_ws, size_t ws_size,
                              hipStream_t stream) {
    const float* emb  = (const float*)d_in[0];
    const float* vals = (const float*)d_in[1];
    const float* W    = (const float*)d_in[2];
    const int*   rows = (const int*)d_in[3];
    const int*   cols = (const int*)d_in[4];
    float* out = (float*)d_out;

    char* ws = (char*)d_ws;
    size_t off = 0;
    auto alloc = [&](size_t bytes) -> void* {
        void* p = ws + off;
        off = (off + bytes + 255) & ~(size_t)255;
        return p;
    };
    // arena: binbuf (CSR build) then reused as gemm output gbuf (build done first)
    size_t g_sz   = (size_t)N_ITEMS * 128 * 2;                  // 25.6 MB
    size_t bin_sz = (size_t)NBINS * CAP_BIN * 8;                // 14.4 MB
    char* arena = (char*)alloc(g_sz > bin_sz ? g_sz : bin_sz);
    int2* binbuf = (int2*)arena;
    u16*  gbuf   = (u16*)arena;

    u16*  hn0     = (u16*)alloc((size_t)N_ITEMS * 128 * 2);
    u16*  hn1     = (u16*)alloc((size_t)N_ITEMS * 128 * 2);
    u16*  hn2     = (u16*)alloc((size_t)N_ITEMS * 128 * 2);
    int2* csr     = (int2*)alloc((size_t)NBINS * CAP_BIN * 8);
    int*  bin_cnt = (int*)alloc((size_t)NBINS * 4);
    int*  cnt_g   = (int*)alloc((size_t)N_ITEMS * 4);
    int*  rstart  = (int*)alloc((size_t)N_ITEMS * 4);
    float* inv0   = (float*)alloc((size_t)N_ITEMS * 4);
    float* inv1   = (float*)alloc((size_t)N_ITEMS * 4);
    float* inv2   = (float*)alloc((size_t)N_ITEMS * 4);
    u16*  Wbf     = (u16*)alloc((size_t)NLAYERS * EMB * EMB * 2);

    // CSR build (binned two-pass)
    hipMemsetAsync(bin_cnt, 0, (size_t)NBINS * 4, stream);
    fill_coarse_k<<<512, 256, 0, stream>>>(rows, cols, vals, bin_cnt, binbuf);
    fill_fine_k<<<NBINS, 256, 0, stream>>>(bin_cnt, binbuf, cnt_g, rstart, csr);

    // W -> bf16
    wconv_k<<<(NLAYERS * EMB * EMB + 255) / 256, 256, 0, stream>>>(W, Wbf);

    // 3 layers: gemm (layer 0 reads f32 emb directly) then spmm
    u16* hn[3] = {hn0, hn1, hn2};
    float* inv[3] = {inv0, inv1, inv2};
    const void* cur = emb;
    for (int L = 0; L < NLAYERS; L++) {
        if (L == 0)
            gemm_k<true><<<(N_ITEMS + 127) / 128, 256, 0, stream>>>(cur, Wbf, gbuf);
        else
            gemm_k<false><<<(N_ITEMS + 127) / 128, 256, 0, stream>>>(cur, Wbf + (size_t)L * EMB * EMB, gbuf);
        spmm_k<<<N_ITEMS / 4, 256, 0, stream>>>(gbuf, rstart, cnt_g, csr, hn[L], inv[L]);
        cur = hn[L];
    }

    // final merge
    merge_k<<<(N_ITEMS * 128 / 4) / 256, 256, 0, stream>>>(
        (const float4*)emb, (const ushort4*)hn0, (const ushort4*)hn1,
        (const ushort4*)hn2, inv0, inv1, inv2, (float4*)out);
}